// Round 1
// baseline (79.164 us; speedup 1.0000x reference)
//
#include <hip/hip_runtime.h>

// NodeConvolution: out[b,s,d] = x[b,2s,d]*w[0,d] + x[b,2s+1,d]*w[1,d]
// Shapes: x (32, 4096, 512) f32, w (2, 512) f32, out (32, 2048, 512) f32.
// Memory-bound: ~403 MB HBM traffic -> ~64 us floor at 6.3 TB/s.

#define D4 128          // D/4 = 512/4 float4 per row
#define D4_SHIFT 7      // log2(D4)

__global__ __launch_bounds__(256) void nodeconv_kernel(
    const float4* __restrict__ x,   // [B*N][D4]
    const float4* __restrict__ w,   // [2][D4]
    float4* __restrict__ out,       // [B*steps][D4]
    int n4)                         // total output float4 count
{
    const int stride = gridDim.x * blockDim.x;   // multiple of D4 by construction
    const int tid = blockIdx.x * blockDim.x + threadIdx.x;

    // stride % D4 == 0  ->  column index d is loop-invariant per thread
    const int d = tid & (D4 - 1);
    const float4 w0 = w[d];
    const float4 w1 = w[D4 + d];

    for (int i = tid; i < n4; i += stride) {
        const int row = i >> D4_SHIFT;           // output row = b*steps + s
        const float4 x0 = x[((2 * row)     << D4_SHIFT) + d];
        const float4 x1 = x[((2 * row + 1) << D4_SHIFT) + d];
        float4 o;
        o.x = x0.x * w0.x + x1.x * w1.x;
        o.y = x0.y * w0.y + x1.y * w1.y;
        o.z = x0.z * w0.z + x1.z * w1.z;
        o.w = x0.w * w0.w + x1.w * w1.w;
        out[i] = o;
    }
}

extern "C" void kernel_launch(void* const* d_in, const int* in_sizes, int n_in,
                              void* d_out, int out_size, void* d_ws, size_t ws_size,
                              hipStream_t stream) {
    const float4* x = (const float4*)d_in[0];
    const float4* w = (const float4*)d_in[1];
    float4* out = (float4*)d_out;

    const int n4 = out_size / 4;                 // 8,388,608 float4s

    const int block = 256;
    // 2048 blocks * 256 threads = 524288 threads; stride is a multiple of 128 (=D4)
    const int grid = 2048;
    nodeconv_kernel<<<grid, block, 0, stream>>>(x, w, out, n4);
}

// Round 3
// 72.462 us; speedup vs baseline: 1.0925x; 1.0925x over previous
//
#include <hip/hip_runtime.h>

// NodeConvolution: out[b,s,d] = x[b,2s,d]*w[0,d] + x[b,2s+1,d]*w[1,d]
// Shapes: x (32, 4096, 512) f32, w (2, 512) f32, out (32, 2048, 512) f32.
// Memory-bound: ~403 MB HBM traffic -> ~64 us floor at 6.3 TB/s copy ceiling.
// R1: 79.2 us (5.09 TB/s). R3: nontemporal via native ext_vector_type + 2x unroll.

#define D4 128          // D/4 float4 per row
#define D4_SHIFT 7      // log2(D4)

typedef float f32x4 __attribute__((ext_vector_type(4)));  // native vector: nontemporal-builtin-compatible

__global__ __launch_bounds__(256) void nodeconv_kernel(
    const f32x4* __restrict__ x,   // [B*N][D4]
    const f32x4* __restrict__ w,   // [2][D4]
    f32x4* __restrict__ out,       // [B*steps][D4]
    int n4)                        // total output float4 count
{
    const int stride = gridDim.x * blockDim.x;   // multiple of D4 by construction
    const int tid = blockIdx.x * blockDim.x + threadIdx.x;

    // stride % D4 == 0 -> column index d is loop-invariant per thread
    const int d = tid & (D4 - 1);
    const f32x4 w0 = w[d];          // weights: tiny, cache-resident
    const f32x4 w1 = w[D4 + d];

    int i = tid;
    // main: 2 outputs per iteration, 4 independent nontemporal loads in flight
    for (; i + stride < n4; i += 2 * stride) {
        const int ia = i;
        const int ib = i + stride;
        const int ra = ia >> D4_SHIFT;
        const int rb = ib >> D4_SHIFT;
        const f32x4 a0 = __builtin_nontemporal_load(&x[((2 * ra)     << D4_SHIFT) + d]);
        const f32x4 a1 = __builtin_nontemporal_load(&x[((2 * ra + 1) << D4_SHIFT) + d]);
        const f32x4 b0 = __builtin_nontemporal_load(&x[((2 * rb)     << D4_SHIFT) + d]);
        const f32x4 b1 = __builtin_nontemporal_load(&x[((2 * rb + 1) << D4_SHIFT) + d]);
        const f32x4 oa = a0 * w0 + a1 * w1;
        const f32x4 ob = b0 * w0 + b1 * w1;
        __builtin_nontemporal_store(oa, &out[ia]);
        __builtin_nontemporal_store(ob, &out[ib]);
    }
    // tail (n4 is a multiple of stride in this config, but keep it general)
    for (; i < n4; i += stride) {
        const int r = i >> D4_SHIFT;
        const f32x4 x0 = __builtin_nontemporal_load(&x[((2 * r)     << D4_SHIFT) + d]);
        const f32x4 x1 = __builtin_nontemporal_load(&x[((2 * r + 1) << D4_SHIFT) + d]);
        const f32x4 o = x0 * w0 + x1 * w1;
        __builtin_nontemporal_store(o, &out[i]);
    }
}

extern "C" void kernel_launch(void* const* d_in, const int* in_sizes, int n_in,
                              void* d_out, int out_size, void* d_ws, size_t ws_size,
                              hipStream_t stream) {
    const f32x4* x = (const f32x4*)d_in[0];
    const f32x4* w = (const f32x4*)d_in[1];
    f32x4* out = (f32x4*)d_out;

    const int n4 = out_size / 4;                 // 8,388,608 float4s

    const int block = 256;
    const int grid = 2048;                       // 8 blocks/CU, 32 waves/CU
    nodeconv_kernel<<<grid, block, 0, stream>>>(x, w, out, n4);
}